// Round 4
// baseline (192.491 us; speedup 1.0000x reference)
//
#include <hip/hip_runtime.h>

// Problem constants (match reference)
#define K_     1056
#define N_     2112
#define M_     1056   // N - K
#define E_     6336   // M * 6
#define NIE_   5280   // M * 5 info-side edges (the only BP state)
#define CAP_   6336   // padded edge-slot extent (stride = d|1 adds <=1/VN); == N_+4K ints
#define DV_    5
#define ROW_   6      // edge 6m+5 is the parity VN K+m
#define NSYM_  528
#define NITER_ 20
#define BATCH_ 1024
#define BS_    512    // R23: back to 8 waves/block, 4 blocks/CU = 32 waves

#define LOG2E_ 1.4426950408889634f
#define AVLO_  (1e-6f * LOG2E_)          // |v2c| floor, bits units
#define AVHI_  (20.0f * LOG2E_)          // |v2c| cap,  bits units
#define QC_    0.99999988f               // tanh-domain cap (unchanged)

// stride(d) = d | 1 : always ODD -> coprime with 32 banks -> Phase A's
// wave-uniform-stride segment reads/writes are conflict-free.
__device__ __forceinline__ int seg_stride(int d) { return d | 1; }

// Bare-instruction transcendentals (R17 win: OCML wrappers inflated the
// hot loop ~2x; inputs always normal-range, <=1 ULP deviation validated
// absmax-0 since R1).
__device__ __forceinline__ float fexp2(float x) { return __builtin_amdgcn_exp2f(x); }
__device__ __forceinline__ float flog2(float x) { return __builtin_amdgcn_logf(x); }
__device__ __forceinline__ float frcp(float x)  { return __builtin_amdgcn_rcpf(x); }

// -------------------------------------------------------------------------
// Single kernel, one block per codeword, 512 threads / 8 waves.
// == R23: v2c-in-place BP (extrinsic computed by Phase A) ==
//
// R20-R22 occupancy ladder: 32 waves+scratch-spill (117us) beat
// 28 waves+small-spill (125us) beat 24 waves+clean (135us) -> waves
// dominate, spill second-order. The winning point (32 waves AND zero
// spill) needs the live set under (512,8)'s 64-unified-reg cap
// (32 arch + 32 accum).
//
// R23 restructure: Phase A, after accumulating mg over its odd-stride
// segment, writes the EXTRINSIC v2c = mg - slot back into each edge
// slot in place (2nd sequential pass, conflict-free). Phase B reads
// v2c at the edge address and overwrites it with r (same address).
// Eliminates: the c2v[3][5] register file (R20), the s_marg array and
// its gather, vnp's slot field (ep = 5 x 16-bit byte-offsets packed
// into 3 regs/CN). Persistent state: pv/od/lr/t5 (12) + ep (9) = 21
// dwords, peak live ~40 <= 64 -> AGPR-handled, zero scratch (check:
// WRITE_SIZE == ~8450 KB pure output).
// Numerics: mg keeps the exact d+=2 accumulation; v2c = mg - slot is
// the identical subtraction B did as mgv - c2v; iter-0 reads zeroed
// slots (lr + 0.0 exact); loop {A;B} x 20 + epilogue = exactly 20 CN
// updates, matching the reference scan. absmax 0 by construction.
// R18 lesson: index-CSR gather in Phase A regressed; sequential float
// segments retained.
//
// Base-2 LLR domain after demap (LLR_hat = LLR * log2e). LDS ~26 KB:
//   s_all[CAP_]: build: [0..N) staging, [N..N+4K)=[N..CAP) int scratch;
//                BP: [0..CAP) edge slots (A: r -> v2c, B: v2c -> r)
//
// Structure: H = [A | I]; parity VN deg-1 -> per-check constant t5;
// degree-sorted slots (wave-uniform Phase A trips); scan-free bases from
// 32-bin histogram; atomic build order only permutes accumulation order
// (validated order-independent R4-R22, absmax 0).
//
// CN math (product form, prefix/suffix partial products, bits domain):
//   t = copysign((1-2^-av)/(1+2^-av), v2c);  q_j = t5 * prod_{i!=j} t_i
//   q = med3(q, -QC, QC);  r = log2((1+q)/(1-q))
// -------------------------------------------------------------------------
__global__ __launch_bounds__(BS_, 8) void link_kernel(
    const int*   __restrict__ bits,      // [B,K]
    const int*   __restrict__ a_idx,     // [M,DV]
    const float* __restrict__ points_re, // [16]
    const float* __restrict__ points_im, // [16]
    const float* __restrict__ noise_re,  // [B,NSYM]
    const float* __restrict__ noise_im,  // [B,NSYM]
    const float* __restrict__ ebno_db,   // [1]
    const int*   __restrict__ edge_vn,   // [E]
    float*       __restrict__ out)       // [2,B,K]
{
#pragma clang fp contract(off)
    const int b   = blockIdx.x;
    const int tid = threadIdx.x;

    __shared__ float s_all[CAP_];
    __shared__ float s_pre[16];
    __shared__ float s_pim[16];
    __shared__ int   s_hist[32];
    __shared__ int   s_binStart[32];
    __shared__ int   s_binBase[32];

    float* s_mem = s_all;                // staging, later edge-slot array
    char*  sb    = (char*)s_all;         // byte-addressed view for Phase B

    // build scratch aliases [N..CAP) (demap uses [0..N))
    int* sc        = (int*)(s_all + N_);
    int* s_deg     = sc;                 // [K] degree
    int* s_perm    = sc + K_;            // [K] slot -> v | deg<<16
    int* s_offslot = sc + 2 * K_;        // [K] v -> base | slot<<16
    int* s_cnt     = sc + 3 * K_;        // [K] edge-fill cursors

    if (tid < 16) {
        s_pre[tid] = points_re[tid];
        s_pim[tid] = points_im[tid];
    }
    if (tid < 32) s_hist[tid] = 0;

    const float eb    = ebno_db[0];
    const float no    = 1.0f / ((powf(10.0f, eb / 10.0f) * 0.5f) * 4.0f);
    const float sigma = sqrtf(no / 2.0f);

    // ---- stage info bits (0/1 floats); output0 = bits.astype(f32) ----
    for (int i = tid; i < K_; i += BS_) {
        int v = bits[b * K_ + i];
        s_mem[i] = (float)v;
        out[b * K_ + i] = (float)v;
    }
    __syncthreads();

    // ---- parity: XOR of DV gathered info bits; zero build counters ----
    for (int m = tid; m < M_; m += BS_) {
        float acc = 0.0f;
        #pragma unroll
        for (int d = 0; d < DV_; ++d) acc += s_mem[a_idx[m * DV_ + d]];
        s_mem[K_ + m] = (float)(((int)acc) & 1);
    }
    for (int v = tid; v < K_; v += BS_) { s_deg[v] = 0; s_cnt[v] = 0; }
    __syncthreads();

    // ---- QAM + AWGN + exact APP demap, PER-BIT streaming (R19) ----
    // ---- overlapped: VN degree count (disjoint LDS region)       ----
    for (int s = tid; s < NSYM_; s += BS_) {
        int c0 = (int)s_mem[4 * s + 0];
        int c1 = (int)s_mem[4 * s + 1];
        int c2 = (int)s_mem[4 * s + 2];
        int c3 = (int)s_mem[4 * s + 3];
        int sym = c0 * 8 + c1 * 4 + c2 * 2 + c3;
        float yre = s_pre[sym] + sigma * noise_re[b * NSYM_ + s];
        float yim = s_pim[sym] + sigma * noise_im[b * NSYM_ + s];
        #pragma unroll
        for (int j = 0; j < 4; ++j) {
            // pass 1: maxes for bit j (ascending p, same comparisons)
            float m0 = -1e30f, m1 = -1e30f;
            #pragma unroll
            for (int p = 0; p < 16; ++p) {
                float dre  = yre - s_pre[p];
                float dim_ = yim - s_pim[p];
                float lg   = -(dre * dre + dim_ * dim_) / no;
                if (((p >> (3 - j)) & 1) == 0) m0 = fmaxf(m0, lg);
                else                           m1 = fmaxf(m1, lg);
            }
            // pass 2: sums for bit j (identical fp sequence, ascending p)
            float sum0 = 0.0f, sum1 = 0.0f;
            #pragma unroll
            for (int p = 0; p < 16; ++p) {
                float dre  = yre - s_pre[p];
                float dim_ = yim - s_pim[p];
                float lg   = -(dre * dre + dim_ * dim_) / no;
                if (((p >> (3 - j)) & 1) == 0) sum0 += __expf(lg - m0);
                else                           sum1 += __expf(lg - m1);
            }
            float llr = (m0 + __logf(sum0)) - (m1 + __logf(sum1));
            s_mem[4 * s + j] = llr * LOG2E_;
        }
    }
    for (int idx = tid; idx < NIE_; idx += BS_) {
        int m = idx / 5, j = idx - m * 5;
        atomicAdd(&s_deg[edge_vn[m * ROW_ + j]], 1);
    }
    __syncthreads();

    // ---- degree histogram -> arithmetic segment bases (scan-free) ----
    for (int v = tid; v < K_; v += BS_) atomicAdd(&s_hist[s_deg[v] & 31], 1);
    __syncthreads();
    if (tid == 0) {
        int accS = 0, accB = 0;
        for (int d = 0; d < 32; ++d) {
            int c = s_hist[d];
            s_binStart[d] = accS;
            s_binBase[d]  = accB;
            s_hist[d]     = accS;        // reuse as sort cursor
            accS += c;
            accB += c * seg_stride(d);   // odd stride -> conflict-free
        }
    }
    __syncthreads();
    for (int v = tid; v < K_; v += BS_) {   // counting sort by degree
        int d    = s_deg[v];
        int slot = atomicAdd(&s_hist[d & 31], 1);
        int base = s_binBase[d] + (slot - s_binStart[d]) * seg_stride(d);
        s_perm[slot]  = v | (d << 16);
        s_offslot[v]  = base | (slot << 16);
    }
    __syncthreads();

    // ---- capture iteration-invariant state in registers ----
    int      pv[3];                      // slot -> VN id
    unsigned od[3];                      // base | deg<<16
    float    lr[3];                      // channel LLR_hat of owned VN
    #pragma unroll
    for (int k = 0; k < 3; ++k) {
        int s = tid + BS_ * k;
        if (s < K_) {
            int w = s_perm[s];
            int v = w & 0xFFFF;
            int d = w >> 16;
            int base = s_binBase[d] + (s - s_binStart[d]) * seg_stride(d);
            pv[k] = v;
            od[k] = (unsigned)base | ((unsigned)d << 16);
            lr[k] = s_mem[v];
        } else { pv[k] = 0; od[k] = 0; lr[k] = 0.0f; }
    }
    float    t5[3];
    unsigned ep[3][3];                   // R23: 5 x 16-bit edge byte-offsets, packed
    #pragma unroll
    for (int kk = 0; kk < 3; ++kk) {
        int m = tid + BS_ * kk;
        if (m < M_) {
            unsigned eb5[5];
            #pragma unroll
            for (int j = 0; j < 5; ++j) {
                int v = edge_vn[m * ROW_ + j];
                int r = atomicAdd(&s_cnt[v], 1);
                int w = s_offslot[v];
                int epos = (w & 0xFFFF) + r;
                eb5[j] = (unsigned)(epos << 2);      // byte offset < 25344
            }
            ep[kk][0] = eb5[0] | (eb5[1] << 16);
            ep[kk][1] = eb5[2] | (eb5[3] << 16);
            ep[kk][2] = eb5[4];
            float lrP = s_mem[K_ + m];
            float av  = __builtin_amdgcn_fmed3f(fabsf(lrP), AVLO_, AVHI_);
            float e   = fexp2(-av);
            float tm  = (1.0f - e) * frcp(1.0f + e);
            t5[kk] = copysignf(tm, lrP);
        } else {
            t5[kk] = 0.0f;
            ep[kk][0] = 0; ep[kk][1] = 0; ep[kk][2] = 0;
        }
    }
    __syncthreads();
    // staging fully consumed -> zero the edge-slot array (iter-0 c2v = 0)
    for (int i = tid; i < CAP_; i += BS_) s_mem[i] = 0.0f;
    __syncthreads();

    // ---- sum-product BP, flooding (bits domain), {A; B} x NITER ----
    for (int it = 0; it < NITER_; ++it) {
        // Phase A: accumulate mg over the odd-stride segment (exact d+=2
        // order), then write extrinsic v2c = mg - slot IN PLACE
        // (sequential conflict-free 2nd pass). Slots: r -> v2c.
        #pragma unroll
        for (int k = 0; k < 3; ++k) {
            int s = tid + BS_ * k;
            if (s < K_) {
                int base = (int)(od[k] & 0xFFFFu);
                int dg   = (int)(od[k] >> 16);
                float mg = lr[k];
                int d = 0;
                for (; d + 1 < dg; d += 2) {
                    mg += s_mem[base + d];
                    mg += s_mem[base + d + 1];
                }
                if (d < dg) mg += s_mem[base + d];
                for (int i = 0; i < dg; ++i)
                    s_mem[base + i] = mg - s_mem[base + i];
            }
        }
        __syncthreads();
        // Phase B: CN update; read v2c at edge address, overwrite with r
        // (same address). 2 random LDS ops/edge. Bare v_exp/v_log/v_rcp.
        #pragma unroll
        for (int kk = 0; kk < 3; ++kk) {
            int m = tid + BS_ * kk;
            if (m < M_) {
                unsigned a0 =  ep[kk][0] & 0xFFFFu;
                unsigned a1 =  ep[kk][0] >> 16;
                unsigned a2 =  ep[kk][1] & 0xFFFFu;
                unsigned a3 =  ep[kk][1] >> 16;
                unsigned a4 =  ep[kk][2];
                unsigned ad[5] = { a0, a1, a2, a3, a4 };
                float tj[5];
                #pragma unroll
                for (int j = 0; j < 5; ++j) {
                    float v2c = *(const float*)(sb + ad[j]);
                    float av  = __builtin_amdgcn_fmed3f(fabsf(v2c), AVLO_, AVHI_);
                    float e   = fexp2(-av);
                    float tm  = (1.0f - e) * frcp(1.0f + e);
                    tj[j] = copysignf(tm, v2c);
                }
                float qv[5];
                float pr = t5[kk];
                #pragma unroll
                for (int j = 0; j < 5; ++j) { qv[j] = pr; pr *= tj[j]; }
                float sf = 1.0f;
                #pragma unroll
                for (int j = 4; j >= 0; --j) { qv[j] *= sf; sf *= tj[j]; }
                #pragma unroll
                for (int j = 0; j < 5; ++j) {
                    float q = __builtin_amdgcn_fmed3f(qv[j], -QC_, QC_);
                    float r = flog2((1.0f + q) * frcp(1.0f - q));
                    *(float*)(sb + ad[j]) = r;
                }
            }
        }
        __syncthreads();
    }

    // ---- epilogue: final marginal + hard decision on info VNs ----
    #pragma unroll
    for (int k = 0; k < 3; ++k) {
        int s = tid + BS_ * k;
        if (s < K_) {
            int base = (int)(od[k] & 0xFFFFu);
            int dg   = (int)(od[k] >> 16);
            float mg = lr[k];
            int d = 0;
            for (; d + 1 < dg; d += 2) {
                mg += s_mem[base + d];
                mg += s_mem[base + d + 1];
            }
            if (d < dg) mg += s_mem[base + d];
            out[(size_t)BATCH_ * K_ + b * K_ + pv[k]] = (mg < 0.0f) ? 1.0f : 0.0f;
        }
    }
}

extern "C" void kernel_launch(void* const* d_in, const int* in_sizes, int n_in,
                              void* d_out, int out_size, void* d_ws, size_t ws_size,
                              hipStream_t stream) {
    const int*   bits    = (const int*)  d_in[0];
    const int*   a_idx   = (const int*)  d_in[1];
    // d_in[2] = edge_cn (implicit: contiguous groups of 6) — unused
    const int*   edge_vn = (const int*)  d_in[3];
    const float* pre     = (const float*)d_in[4];
    const float* pim     = (const float*)d_in[5];
    const float* nre     = (const float*)d_in[6];
    const float* nim     = (const float*)d_in[7];
    const float* ebno    = (const float*)d_in[8];

    link_kernel<<<BATCH_, BS_, 0, stream>>>(bits, a_idx, pre, pim, nre, nim,
                                            ebno, edge_vn, (float*)d_out);
}

// Round 5
// 181.534 us; speedup vs baseline: 1.0604x; 1.0604x over previous
//
#include <hip/hip_runtime.h>

// Problem constants (match reference)
#define K_     1056
#define N_     2112
#define M_     1056   // N - K
#define E_     6336   // M * 6
#define NIE_   5280   // M * 5 info-side edges (the only BP state)
#define CAP_   6336   // padded c2v extent upper bound (stride = d|1 adds <=1/VN)
#define ALL_   7392   // CAP_ + K_ : c2v + marg unified array
#define DV_    5
#define ROW_   6      // edge 6m+5 is the parity VN K+m
#define NSYM_  528
#define NITER_ 20
#define BATCH_ 1024
#define BS_    1024   // R24: 16 waves/block, 2 blocks/CU = 32 waves, kmax=2
#define KMAX_  2      // ceil(K_/BS_) work trips per thread

#define LOG2E_ 1.4426950408889634f
#define AVLO_  (1e-6f * LOG2E_)          // |v2c| floor, bits units
#define AVHI_  (20.0f * LOG2E_)          // |v2c| cap,  bits units
#define QC_    0.99999988f               // tanh-domain cap (unchanged)

// stride(d) = d | 1 : always ODD -> coprime with 32 banks -> Phase A's
// wave-uniform-stride segment reads are conflict-free.
__device__ __forceinline__ int seg_stride(int d) { return d | 1; }

// Bare-instruction transcendentals (R17 win: OCML wrappers inflated the
// hot loop ~2x; inputs always normal-range, <=1 ULP deviation validated
// absmax-0 since R1).
__device__ __forceinline__ float fexp2(float x) { return __builtin_amdgcn_exp2f(x); }
__device__ __forceinline__ float flog2(float x) { return __builtin_amdgcn_logf(x); }
__device__ __forceinline__ float frcp(float x)  { return __builtin_amdgcn_rcpf(x); }

// -------------------------------------------------------------------------
// Single kernel, one block per codeword, 1024 threads / 16 waves.
// == R24: R20 BP structure (best per-iter cost, 117us) at BS=1024 ==
//
// R20-R23 ladder findings:
//   - waves dominate; de-spill via fewer waves (R21 24w, R22 28w) LOSES.
//   - the ~24.6MB baseline spill at (512,8) is structural (~12 dw/thread,
//     identical in R19/R20/R23) and mostly L2-hidden.
//   - R23's in-place extrinsic added ~2xdg LDS ops/VN/iter -> regressed.
// R24: cut per-thread work multiplicity instead of per-item state.
// BS=1024, kmax=2 (trip 2 = 32 threads only): persistent state
// vnp[2][5]+c2v[2][5]+t5/od/lr/pv = 28 dw, peak live ~45 < 64-reg cap
// at 8 waves/EU -> zero scratch (check: WRITE_SIZE == 8448 KB) while
// KEEPING 32 waves/CU (16 waves x 2 blocks; LDS 2x30.2 <= 160 KB;
// grid 1024 = 2 tail-free rounds of 512 resident blocks).
// BP inner sequences verbatim from R20 -> absmax 0 by construction
// (thread->work mapping changes = atomic-rank permutation class,
// validated order-independent R4-R23).
// R18 lesson: index-CSR gather in Phase A regressed; sequential float
// segments retained.
//
// Base-2 LLR domain after demap (LLR_hat = LLR * log2e). LDS ~30 KB:
//   s_all[7392]: build: [0..N) staging, [N..N+4K) int scratch;
//                BP: [0..CAP) c2v odd-stride VN-major segments (r-values,
//                    written by B, read by A),
//                    [CAP..) slot-indexed marginals
//
// Structure: H = [A | I]; parity VN deg-1 -> per-check constant t5;
// degree-sorted slots (wave-uniform Phase A trips); scan-free bases from
// 32-bin histogram; atomic build order only permutes accumulation order.
//
// CN math (product form, prefix/suffix partial products, bits domain):
//   t = copysign((1-2^-av)/(1+2^-av), v2c);  q_j = t5 * prod_{i!=j} t_i
//   q = med3(q, -QC, QC);  r = log2((1+q)/(1-q))
// -------------------------------------------------------------------------
__global__ __launch_bounds__(BS_, 8) void link_kernel(
    const int*   __restrict__ bits,      // [B,K]
    const int*   __restrict__ a_idx,     // [M,DV]
    const float* __restrict__ points_re, // [16]
    const float* __restrict__ points_im, // [16]
    const float* __restrict__ noise_re,  // [B,NSYM]
    const float* __restrict__ noise_im,  // [B,NSYM]
    const float* __restrict__ ebno_db,   // [1]
    const int*   __restrict__ edge_vn,   // [E]
    float*       __restrict__ out)       // [2,B,K]
{
#pragma clang fp contract(off)
    const int b   = blockIdx.x;
    const int tid = threadIdx.x;

    __shared__ float s_all[ALL_];
    __shared__ float s_pre[16];
    __shared__ float s_pim[16];
    __shared__ int   s_hist[32];
    __shared__ int   s_binStart[32];
    __shared__ int   s_binBase[32];

    float* s_mem  = s_all;               // staging, later c2v r-values [0..CAP)
    float* s_marg = s_all + CAP_;        // BP marginals [CAP..ALL)

    // build scratch aliases [N..N+4K) (inside s_all; demap uses [0..N))
    int* sc        = (int*)(s_all + N_);
    int* s_deg     = sc;                 // [K] degree
    int* s_perm    = sc + K_;            // [K] slot -> v | deg<<16
    int* s_offslot = sc + 2 * K_;        // [K] v -> base | slot<<16
    int* s_cnt     = sc + 3 * K_;        // [K] edge-fill cursors

    if (tid < 16) {
        s_pre[tid] = points_re[tid];
        s_pim[tid] = points_im[tid];
    }
    if (tid < 32) s_hist[tid] = 0;

    const float eb    = ebno_db[0];
    const float no    = 1.0f / ((powf(10.0f, eb / 10.0f) * 0.5f) * 4.0f);
    const float sigma = sqrtf(no / 2.0f);

    // ---- stage info bits (0/1 floats); output0 = bits.astype(f32) ----
    for (int i = tid; i < K_; i += BS_) {
        int v = bits[b * K_ + i];
        s_mem[i] = (float)v;
        out[b * K_ + i] = (float)v;
    }
    __syncthreads();

    // ---- parity: XOR of DV gathered info bits; zero build counters ----
    for (int m = tid; m < M_; m += BS_) {
        float acc = 0.0f;
        #pragma unroll
        for (int d = 0; d < DV_; ++d) acc += s_mem[a_idx[m * DV_ + d]];
        s_mem[K_ + m] = (float)(((int)acc) & 1);
    }
    for (int v = tid; v < K_; v += BS_) { s_deg[v] = 0; s_cnt[v] = 0; }
    __syncthreads();

    // ---- QAM + AWGN + exact APP demap, PER-BIT streaming (R19) ----
    // ---- overlapped: VN degree count (disjoint LDS region)       ----
    for (int s = tid; s < NSYM_; s += BS_) {
        int c0 = (int)s_mem[4 * s + 0];
        int c1 = (int)s_mem[4 * s + 1];
        int c2 = (int)s_mem[4 * s + 2];
        int c3 = (int)s_mem[4 * s + 3];
        int sym = c0 * 8 + c1 * 4 + c2 * 2 + c3;
        float yre = s_pre[sym] + sigma * noise_re[b * NSYM_ + s];
        float yim = s_pim[sym] + sigma * noise_im[b * NSYM_ + s];
        #pragma unroll
        for (int j = 0; j < 4; ++j) {
            // pass 1: maxes for bit j (ascending p, same comparisons)
            float m0 = -1e30f, m1 = -1e30f;
            #pragma unroll
            for (int p = 0; p < 16; ++p) {
                float dre  = yre - s_pre[p];
                float dim_ = yim - s_pim[p];
                float lg   = -(dre * dre + dim_ * dim_) / no;
                if (((p >> (3 - j)) & 1) == 0) m0 = fmaxf(m0, lg);
                else                           m1 = fmaxf(m1, lg);
            }
            // pass 2: sums for bit j (identical fp sequence, ascending p)
            float sum0 = 0.0f, sum1 = 0.0f;
            #pragma unroll
            for (int p = 0; p < 16; ++p) {
                float dre  = yre - s_pre[p];
                float dim_ = yim - s_pim[p];
                float lg   = -(dre * dre + dim_ * dim_) / no;
                if (((p >> (3 - j)) & 1) == 0) sum0 += __expf(lg - m0);
                else                           sum1 += __expf(lg - m1);
            }
            float llr = (m0 + __logf(sum0)) - (m1 + __logf(sum1));
            s_mem[4 * s + j] = llr * LOG2E_;
        }
    }
    for (int idx = tid; idx < NIE_; idx += BS_) {
        int m = idx / 5, j = idx - m * 5;
        atomicAdd(&s_deg[edge_vn[m * ROW_ + j]], 1);
    }
    __syncthreads();

    // ---- degree histogram -> arithmetic segment bases (scan-free) ----
    for (int v = tid; v < K_; v += BS_) atomicAdd(&s_hist[s_deg[v] & 31], 1);
    __syncthreads();
    if (tid == 0) {
        int accS = 0, accB = 0;
        for (int d = 0; d < 32; ++d) {
            int c = s_hist[d];
            s_binStart[d] = accS;
            s_binBase[d]  = accB;
            s_hist[d]     = accS;        // reuse as sort cursor
            accS += c;
            accB += c * seg_stride(d);   // odd stride -> conflict-free
        }
    }
    __syncthreads();
    for (int v = tid; v < K_; v += BS_) {   // counting sort by degree
        int d    = s_deg[v];
        int slot = atomicAdd(&s_hist[d & 31], 1);
        int base = s_binBase[d] + (slot - s_binStart[d]) * seg_stride(d);
        s_perm[slot]  = v | (d << 16);
        s_offslot[v]  = base | (slot << 16);
    }
    __syncthreads();

    // ---- capture iteration-invariant state in registers ----
    int      pv[KMAX_];                  // slot -> VN id
    unsigned od[KMAX_];                  // base | deg<<16
    float    lr[KMAX_];                  // channel LLR_hat of owned VN
    #pragma unroll
    for (int k = 0; k < KMAX_; ++k) {
        int s = tid + BS_ * k;
        if (s < K_) {
            int w = s_perm[s];
            int v = w & 0xFFFF;
            int d = w >> 16;
            int base = s_binBase[d] + (s - s_binStart[d]) * seg_stride(d);
            pv[k] = v;
            od[k] = (unsigned)base | ((unsigned)d << 16);
            lr[k] = s_mem[v];
            s_marg[s] = lr[k];           // iter-0 marginal == channel LLR
        } else { pv[k] = 0; od[k] = 0; lr[k] = 0.0f; }
    }
    float    t5[KMAX_];
    unsigned vnp[KMAX_][5];              // slotByte | eposByte<<16 (byte-packed)
    float    c2v[KMAX_][5];              // c2v register file (single writer = owner)
    #pragma unroll
    for (int kk = 0; kk < KMAX_; ++kk) {
        int m = tid + BS_ * kk;
        if (m < M_) {
            #pragma unroll
            for (int j = 0; j < 5; ++j) {
                int v = edge_vn[m * ROW_ + j];
                int r = atomicAdd(&s_cnt[v], 1);
                int w = s_offslot[v];
                int slot = w >> 16;
                int epos = (w & 0xFFFF) + r;
                vnp[kk][j] = (unsigned)(slot << 2) | ((unsigned)(epos << 2) << 16);
                c2v[kk][j] = 0.0f;
            }
            float lrP = s_mem[K_ + m];
            float av  = __builtin_amdgcn_fmed3f(fabsf(lrP), AVLO_, AVHI_);
            float e   = fexp2(-av);
            float tm  = (1.0f - e) * frcp(1.0f + e);
            t5[kk] = copysignf(tm, lrP);
        } else {
            t5[kk] = 0.0f;
            #pragma unroll
            for (int j = 0; j < 5; ++j) { vnp[kk][j] = 0; c2v[kk][j] = 0.0f; }
        }
    }
    __syncthreads();   // staging fully consumed; [0..CAP) becomes r-value array

    // ---- sum-product BP, flooding (bits domain), {B; A} x NITER ----
    for (int it = 0; it < NITER_; ++it) {
        // Phase B: CN update; old c2v from REGISTERS; bare v_exp/v_log/
        // v_rcp transcendentals. 2 random LDS ops/edge:
        // marg gather (ds offset folds CAP_*4) + r scatter-write.
        #pragma unroll
        for (int kk = 0; kk < KMAX_; ++kk) {
            int m = tid + BS_ * kk;
            if (m < M_) {
                float tj[5];
                #pragma unroll
                for (int j = 0; j < 5; ++j) {
                    unsigned w = vnp[kk][j];
                    float mgv = *(const float*)((const char*)s_all +
                                 ((w & 0xFFFFu) + (unsigned)(CAP_ * 4)));
                    float v2c = mgv - c2v[kk][j];
                    float av  = __builtin_amdgcn_fmed3f(fabsf(v2c), AVLO_, AVHI_);
                    float e   = fexp2(-av);
                    float tm  = (1.0f - e) * frcp(1.0f + e);
                    tj[j] = copysignf(tm, v2c);
                }
                float qv[5];
                float pr = t5[kk];
                #pragma unroll
                for (int j = 0; j < 5; ++j) { qv[j] = pr; pr *= tj[j]; }
                float sf = 1.0f;
                #pragma unroll
                for (int j = 4; j >= 0; --j) { qv[j] *= sf; sf *= tj[j]; }
                #pragma unroll
                for (int j = 0; j < 5; ++j) {
                    float q = __builtin_amdgcn_fmed3f(qv[j], -QC_, QC_);
                    float r = flog2((1.0f + q) * frcp(1.0f - q));
                    c2v[kk][j] = r;
                    *(float*)((char*)s_all + (vnp[kk][j] >> 16)) = r;
                }
            }
        }
        __syncthreads();
        // Phase A: slot-indexed marginals; odd-stride sequential float
        // segments (R18 lesson: beats index-CSR gather). Last iteration
        // doubles as the final marginal + hard decision.
        #pragma unroll
        for (int k = 0; k < KMAX_; ++k) {
            int s = tid + BS_ * k;
            if (s < K_) {
                int base = (int)(od[k] & 0xFFFFu);
                int dg   = (int)(od[k] >> 16);
                float mg = lr[k];
                int d = 0;
                for (; d + 1 < dg; d += 2) {
                    mg += s_mem[base + d];
                    mg += s_mem[base + d + 1];
                }
                if (d < dg) mg += s_mem[base + d];
                s_marg[s] = mg;
                if (it == NITER_ - 1)
                    out[(size_t)BATCH_ * K_ + b * K_ + pv[k]] =
                        (mg < 0.0f) ? 1.0f : 0.0f;
            }
        }
        __syncthreads();
    }
}

extern "C" void kernel_launch(void* const* d_in, const int* in_sizes, int n_in,
                              void* d_out, int out_size, void* d_ws, size_t ws_size,
                              hipStream_t stream) {
    const int*   bits    = (const int*)  d_in[0];
    const int*   a_idx   = (const int*)  d_in[1];
    // d_in[2] = edge_cn (implicit: contiguous groups of 6) — unused
    const int*   edge_vn = (const int*)  d_in[3];
    const float* pre     = (const float*)d_in[4];
    const float* pim     = (const float*)d_in[5];
    const float* nre     = (const float*)d_in[6];
    const float* nim     = (const float*)d_in[7];
    const float* ebno    = (const float*)d_in[8];

    link_kernel<<<BATCH_, BS_, 0, stream>>>(bits, a_idx, pre, pim, nre, nim,
                                            ebno, edge_vn, (float*)d_out);
}

// Round 6
// 177.804 us; speedup vs baseline: 1.0826x; 1.0210x over previous
//
#include <hip/hip_runtime.h>

// Problem constants (match reference)
#define K_     1056
#define N_     2112
#define M_     1056   // N - K
#define E_     6336   // M * 6
#define NIE_   5280   // M * 5 info-side edges (the only BP state)
#define CAP_   6336   // padded c2v extent upper bound (stride = d|1 adds <=1/VN)
#define ALL_   7392   // CAP_ + K_ : c2v + marg unified array (float2 units)
#define DV_    5
#define ROW_   6      // edge 6m+5 is the parity VN K+m
#define NSYM_  528
#define NITER_ 20
#define BATCH_ 1024
#define BS_    1024   // 16 waves/block, 2 blocks/CU = 32 waves
#define KMAX_  2      // ceil(K_/BS_) work trips per thread
#define NCW_   2      // R25: codewords per block (float2-packed payload)

#define LOG2E_ 1.4426950408889634f
#define AVLO_  (1e-6f * LOG2E_)          // |v2c| floor, bits units
#define AVHI_  (20.0f * LOG2E_)          // |v2c| cap,  bits units
#define QC_    0.99999988f               // tanh-domain cap (unchanged)

// stride(d) = d | 1 : always ODD -> coprime with the 16 bank-pairs of a
// b64 access -> Phase A's wave-uniform-stride segment reads stay
// conflict-free in the float2 layout (uniform 4 lanes/bank).
__device__ __forceinline__ int seg_stride(int d) { return d | 1; }

// Bare-instruction transcendentals (R17 win: OCML wrappers inflated the
// hot loop ~2x; inputs always normal-range, <=1 ULP deviation validated
// absmax-0 since R1).
__device__ __forceinline__ float fexp2(float x) { return __builtin_amdgcn_exp2f(x); }
__device__ __forceinline__ float flog2(float x) { return __builtin_amdgcn_logf(x); }
__device__ __forceinline__ float frcp(float x)  { return __builtin_amdgcn_rcpf(x); }

// -------------------------------------------------------------------------
// Single kernel, TWO codewords per block, 1024 threads / 16 waves.
// == R25: float2-packed dual-codeword BP ==
//
// R20-R24 ladder verdict: occupancy axis exhausted (32 waves + zero spill
// = 120.9 us, R24) and the (512,8) spill was prologue-only/hidden (R20
// 116.9 us best). Counter-derived budget: the per-CU LDS unit (shared by
// 4 SIMDs) carries ~860 wave-ops/iter + 76k conflict cycles (26% of
// runtime) -> LDS issue is co-binding with VALU/trans. Per-edge math
// (15 VALU + 4 trans) is at its exact-arithmetic floor.
//
// R25: the Tanner graph is IDENTICAL for all codewords -> pair codewords
// b0=2*blk, b1=2*blk+1 and store every BP value as float2 (.x=cw0,
// .y=cw1). Every LDS instruction in the hot loop becomes b64 and serves
// BOTH codewords: per-codeword LDS ops, barriers, loop overhead, and the
// whole build phase are HALVED. Component math stays scalar -> per-
// codeword fp sequences verbatim R20 -> absmax 0 by construction
// (thread->rank remapping = validated order-independence class R4-R24).
// Geometry: grid 512 (tail-free), LDS 59.5KB -> 2 blocks/CU, 32 waves.
//
// LDS map (float2 units, s_all2[7392] = 59136 B):
//   [0..CAP)   build: [0..N) staging (VN i -> {llr_cw0, llr_cw1}),
//              [N..N+2112) = 4224 ints of build scratch;
//              BP: c2v odd-stride VN-major segments (r-values)
//   [CAP..ALL) slot-indexed marginals (float2)
//
// Structure: H = [A | I]; parity VN deg-1 -> per-check constant t5;
// degree-sorted slots (wave-uniform Phase A trips); scan-free bases from
// 32-bin histogram; od packs base|deg<<13|pv<<18.
//
// CN math per component (prefix/suffix partial products, bits domain):
//   t = copysign((1-2^-av)/(1+2^-av), v2c);  q_j = t5 * prod_{i!=j} t_i
//   q = med3(q, -QC, QC);  r = log2((1+q)/(1-q))
// -------------------------------------------------------------------------
__global__ __launch_bounds__(BS_, 8) void link_kernel(
    const int*   __restrict__ bits,      // [B,K]
    const int*   __restrict__ a_idx,     // [M,DV]
    const float* __restrict__ points_re, // [16]
    const float* __restrict__ points_im, // [16]
    const float* __restrict__ noise_re,  // [B,NSYM]
    const float* __restrict__ noise_im,  // [B,NSYM]
    const float* __restrict__ ebno_db,   // [1]
    const int*   __restrict__ edge_vn,   // [E]
    float*       __restrict__ out)       // [2,B,K]
{
#pragma clang fp contract(off)
    const int blk = blockIdx.x;
    const int b0  = blk * NCW_;          // codeword 0 (component .x)
    const int b1  = b0 + 1;              // codeword 1 (component .y)
    const int tid = threadIdx.x;

    __shared__ float2 s_all2[ALL_];
    __shared__ float  s_pre[16];
    __shared__ float  s_pim[16];
    __shared__ int    s_hist[32];
    __shared__ int    s_binStart[32];
    __shared__ int    s_binBase[32];

    float* s_f = (float*)s_all2;         // scalar view (component access)
    char*  sb  = (char*)s_all2;          // byte view (Phase B addressing)

    // build scratch aliases: float2 [N..N+2112) = 4224 ints (demap uses [0..N))
    int* sc        = (int*)(s_all2 + N_);
    int* s_deg     = sc;                 // [K] degree
    int* s_perm    = sc + K_;            // [K] slot -> v | deg<<16
    int* s_offslot = sc + 2 * K_;        // [K] v -> base | slot<<16
    int* s_cnt     = sc + 3 * K_;        // [K] edge-fill cursors

    if (tid < 16) {
        s_pre[tid] = points_re[tid];
        s_pim[tid] = points_im[tid];
    }
    if (tid < 32) s_hist[tid] = 0;

    const float eb    = ebno_db[0];
    const float no    = 1.0f / ((powf(10.0f, eb / 10.0f) * 0.5f) * 4.0f);
    const float sigma = sqrtf(no / 2.0f);

    // ---- stage info bits (0/1 floats, both codewords); out0 = bits ----
    for (int i = tid; i < K_; i += BS_) {
        int v0 = bits[b0 * K_ + i];
        int v1 = bits[b1 * K_ + i];
        s_f[2 * i + 0] = (float)v0;
        s_f[2 * i + 1] = (float)v1;
        out[b0 * K_ + i] = (float)v0;
        out[b1 * K_ + i] = (float)v1;
    }
    __syncthreads();

    // ---- parity: XOR of DV gathered info bits (both cw, b64 gathers) ----
    for (int m = tid; m < M_; m += BS_) {
        float ax = 0.0f, ay = 0.0f;
        #pragma unroll
        for (int d = 0; d < DV_; ++d) {
            float2 f = s_all2[a_idx[m * DV_ + d]];
            ax += f.x; ay += f.y;
        }
        float2 p;
        p.x = (float)(((int)ax) & 1);
        p.y = (float)(((int)ay) & 1);
        s_all2[K_ + m] = p;
    }
    for (int v = tid; v < K_; v += BS_) { s_deg[v] = 0; s_cnt[v] = 0; }
    __syncthreads();

    // ---- QAM + AWGN + exact APP demap, per-(symbol,codeword) tasks ----
    // ---- overlapped: VN degree count (disjoint LDS region)         ----
    for (int tsk = tid; tsk < NCW_ * NSYM_; tsk += BS_) {
        int cw = (tsk >= NSYM_) ? 1 : 0;
        int s  = tsk - cw * NSYM_;
        int bcw = b0 + cw;
        int c0 = (int)s_f[2 * (4 * s + 0) + cw];
        int c1 = (int)s_f[2 * (4 * s + 1) + cw];
        int c2 = (int)s_f[2 * (4 * s + 2) + cw];
        int c3 = (int)s_f[2 * (4 * s + 3) + cw];
        int sym = c0 * 8 + c1 * 4 + c2 * 2 + c3;
        float yre = s_pre[sym] + sigma * noise_re[bcw * NSYM_ + s];
        float yim = s_pim[sym] + sigma * noise_im[bcw * NSYM_ + s];
        #pragma unroll
        for (int j = 0; j < 4; ++j) {
            // pass 1: maxes for bit j (ascending p, same comparisons)
            float m0 = -1e30f, m1 = -1e30f;
            #pragma unroll
            for (int p = 0; p < 16; ++p) {
                float dre  = yre - s_pre[p];
                float dim_ = yim - s_pim[p];
                float lg   = -(dre * dre + dim_ * dim_) / no;
                if (((p >> (3 - j)) & 1) == 0) m0 = fmaxf(m0, lg);
                else                           m1 = fmaxf(m1, lg);
            }
            // pass 2: sums for bit j (identical fp sequence, ascending p)
            float sum0 = 0.0f, sum1 = 0.0f;
            #pragma unroll
            for (int p = 0; p < 16; ++p) {
                float dre  = yre - s_pre[p];
                float dim_ = yim - s_pim[p];
                float lg   = -(dre * dre + dim_ * dim_) / no;
                if (((p >> (3 - j)) & 1) == 0) sum0 += __expf(lg - m0);
                else                           sum1 += __expf(lg - m1);
            }
            float llr = (m0 + __logf(sum0)) - (m1 + __logf(sum1));
            s_f[2 * (4 * s + j) + cw] = llr * LOG2E_;
        }
    }
    for (int idx = tid; idx < NIE_; idx += BS_) {
        int m = idx / 5, j = idx - m * 5;
        atomicAdd(&s_deg[edge_vn[m * ROW_ + j]], 1);
    }
    __syncthreads();

    // ---- degree histogram -> arithmetic segment bases (scan-free) ----
    for (int v = tid; v < K_; v += BS_) atomicAdd(&s_hist[s_deg[v] & 31], 1);
    __syncthreads();
    if (tid == 0) {
        int accS = 0, accB = 0;
        for (int d = 0; d < 32; ++d) {
            int c = s_hist[d];
            s_binStart[d] = accS;
            s_binBase[d]  = accB;
            s_hist[d]     = accS;        // reuse as sort cursor
            accS += c;
            accB += c * seg_stride(d);   // odd stride -> conflict-free
        }
    }
    __syncthreads();
    for (int v = tid; v < K_; v += BS_) {   // counting sort by degree
        int d    = s_deg[v];
        int slot = atomicAdd(&s_hist[d & 31], 1);
        int base = s_binBase[d] + (slot - s_binStart[d]) * seg_stride(d);
        s_perm[slot]  = v | (d << 16);
        s_offslot[v]  = base | (slot << 16);
    }
    __syncthreads();

    // ---- capture iteration-invariant state in registers ----
    unsigned od[KMAX_];                  // base | deg<<13 | pv<<18
    float2   lr[KMAX_];                  // channel LLR_hat (both cw)
    #pragma unroll
    for (int k = 0; k < KMAX_; ++k) {
        int s = tid + BS_ * k;
        if (s < K_) {
            int w = s_perm[s];
            int v = w & 0xFFFF;
            int d = w >> 16;
            int base = s_binBase[d] + (s - s_binStart[d]) * seg_stride(d);
            od[k] = (unsigned)base | ((unsigned)d << 13) | ((unsigned)v << 18);
            lr[k] = s_all2[v];
            s_all2[CAP_ + s] = lr[k];    // iter-0 marginal == channel LLR
        } else { od[k] = 0; lr[k] = make_float2(0.0f, 0.0f); }
    }
    float2   t5[KMAX_];
    unsigned vnp[KMAX_][5];              // slotByte | eposByte<<16 (x8 units)
    float2   c2v[KMAX_][5];              // c2v register file (both cw)
    #pragma unroll
    for (int kk = 0; kk < KMAX_; ++kk) {
        int m = tid + BS_ * kk;
        if (m < M_) {
            #pragma unroll
            for (int j = 0; j < 5; ++j) {
                int v = edge_vn[m * ROW_ + j];
                int r = atomicAdd(&s_cnt[v], 1);
                int w = s_offslot[v];
                int slot = w >> 16;
                int epos = (w & 0xFFFF) + r;
                vnp[kk][j] = (unsigned)(slot << 3) | ((unsigned)(epos << 3) << 16);
                c2v[kk][j] = make_float2(0.0f, 0.0f);
            }
            float2 lrP = s_all2[K_ + m];
            float avx = __builtin_amdgcn_fmed3f(fabsf(lrP.x), AVLO_, AVHI_);
            float avy = __builtin_amdgcn_fmed3f(fabsf(lrP.y), AVLO_, AVHI_);
            float ex  = fexp2(-avx), ey = fexp2(-avy);
            float tmx = (1.0f - ex) * frcp(1.0f + ex);
            float tmy = (1.0f - ey) * frcp(1.0f + ey);
            t5[kk] = make_float2(copysignf(tmx, lrP.x), copysignf(tmy, lrP.y));
        } else {
            t5[kk] = make_float2(0.0f, 0.0f);
            #pragma unroll
            for (int j = 0; j < 5; ++j) {
                vnp[kk][j] = 0; c2v[kk][j] = make_float2(0.0f, 0.0f);
            }
        }
    }
    __syncthreads();
    // staging + build scratch fully consumed -> zero edge-slot array
    for (int i = tid; i < CAP_; i += BS_) s_all2[i] = make_float2(0.0f, 0.0f);
    __syncthreads();

    // ---- sum-product BP, flooding (bits domain), {B; A} x NITER ----
    for (int it = 0; it < NITER_; ++it) {
        // Phase B: CN update, both codewords per b64 LDS op; old c2v from
        // registers; bare v_exp/v_log/v_rcp. 2 random b64 ops/edge-pair:
        // marg gather (+CAP_*8 folds into ds imm) + r scatter-write.
        #pragma unroll
        for (int kk = 0; kk < KMAX_; ++kk) {
            int m = tid + BS_ * kk;
            if (m < M_) {
                float tjx[5], tjy[5];
                #pragma unroll
                for (int j = 0; j < 5; ++j) {
                    unsigned w = vnp[kk][j];
                    float2 mgv = *(const float2*)(sb +
                                 ((w & 0xFFFFu) + (unsigned)(CAP_ * 8)));
                    float vx = mgv.x - c2v[kk][j].x;
                    float vy = mgv.y - c2v[kk][j].y;
                    float avx = __builtin_amdgcn_fmed3f(fabsf(vx), AVLO_, AVHI_);
                    float avy = __builtin_amdgcn_fmed3f(fabsf(vy), AVLO_, AVHI_);
                    float ex = fexp2(-avx), ey = fexp2(-avy);
                    float tmx = (1.0f - ex) * frcp(1.0f + ex);
                    float tmy = (1.0f - ey) * frcp(1.0f + ey);
                    tjx[j] = copysignf(tmx, vx);
                    tjy[j] = copysignf(tmy, vy);
                }
                float qx[5], qy[5];
                float prx = t5[kk].x, pry = t5[kk].y;
                #pragma unroll
                for (int j = 0; j < 5; ++j) {
                    qx[j] = prx; qy[j] = pry;
                    prx *= tjx[j]; pry *= tjy[j];
                }
                float sfx = 1.0f, sfy = 1.0f;
                #pragma unroll
                for (int j = 4; j >= 0; --j) {
                    qx[j] *= sfx; qy[j] *= sfy;
                    sfx *= tjx[j]; sfy *= tjy[j];
                }
                #pragma unroll
                for (int j = 0; j < 5; ++j) {
                    float qcx = __builtin_amdgcn_fmed3f(qx[j], -QC_, QC_);
                    float qcy = __builtin_amdgcn_fmed3f(qy[j], -QC_, QC_);
                    float rx = flog2((1.0f + qcx) * frcp(1.0f - qcx));
                    float ry = flog2((1.0f + qcy) * frcp(1.0f - qcy));
                    c2v[kk][j] = make_float2(rx, ry);
                    *(float2*)(sb + (vnp[kk][j] >> 16)) = c2v[kk][j];
                }
            }
        }
        __syncthreads();
        // Phase A: slot-indexed marginals; odd-stride sequential b64
        // segment reads (conflict-free, read2_b64-mergeable). Last
        // iteration doubles as the final marginal + hard decision.
        #pragma unroll
        for (int k = 0; k < KMAX_; ++k) {
            int s = tid + BS_ * k;
            if (s < K_) {
                int base = (int)(od[k] & 0x1FFFu);
                int dg   = (int)((od[k] >> 13) & 31u);
                float mgx = lr[k].x, mgy = lr[k].y;
                int d = 0;
                for (; d + 1 < dg; d += 2) {
                    float2 f0 = s_all2[base + d];
                    float2 f1 = s_all2[base + d + 1];
                    mgx += f0.x; mgy += f0.y;
                    mgx += f1.x; mgy += f1.y;
                }
                if (d < dg) {
                    float2 f0 = s_all2[base + d];
                    mgx += f0.x; mgy += f0.y;
                }
                s_all2[CAP_ + s] = make_float2(mgx, mgy);
                if (it == NITER_ - 1) {
                    int pv = (int)(od[k] >> 18);
                    out[(size_t)BATCH_ * K_ + b0 * K_ + pv] = (mgx < 0.0f) ? 1.0f : 0.0f;
                    out[(size_t)BATCH_ * K_ + b1 * K_ + pv] = (mgy < 0.0f) ? 1.0f : 0.0f;
                }
            }
        }
        __syncthreads();
    }
}

extern "C" void kernel_launch(void* const* d_in, const int* in_sizes, int n_in,
                              void* d_out, int out_size, void* d_ws, size_t ws_size,
                              hipStream_t stream) {
    const int*   bits    = (const int*)  d_in[0];
    const int*   a_idx   = (const int*)  d_in[1];
    // d_in[2] = edge_cn (implicit: contiguous groups of 6) — unused
    const int*   edge_vn = (const int*)  d_in[3];
    const float* pre     = (const float*)d_in[4];
    const float* pim     = (const float*)d_in[5];
    const float* nre     = (const float*)d_in[6];
    const float* nim     = (const float*)d_in[7];
    const float* ebno    = (const float*)d_in[8];

    link_kernel<<<BATCH_ / NCW_, BS_, 0, stream>>>(bits, a_idx, pre, pim, nre, nim,
                                                   ebno, edge_vn, (float*)d_out);
}